// Round 1
// baseline (78.293 us; speedup 1.0000x reference)
//
#include <hip/hip_runtime.h>

#define B_  8
#define CI_ 32
#define CO_ 64
#define F_  4
#define H_  64
#define W_  64

// Fully fused single kernel. One block per (b, o-pair): 256 blocks x 1024
// threads (1 block/CU). Each block:
//   1. 64 threads build per-i coefficient weights (summed over f) into LDS:
//        wx0[i] = sum_f Wx[f,o,i,0], wx1[i] = sum_f Wx[f,o,i,1]
//        wy0[i] = sum_f Wy[f,o,i,0], wy1[i] = sum_f Wy[f,o,i,1]
//   2. All 1024 threads stream the 32 v-planes of batch b (one float4 per
//      thread per plane, fully coalesced, L2/L3-resident: v is only 4 MB),
//      accumulating directly into the 3 per-o scalars:
//        SX0 = sum_i wx0[i]*iv[b,i], SX1 = sum_i wx1[i]*iv[b,i]
//        C   = sum_i wy0[i]*T0[b,i] + wy1[i]*T1[b,i]
//      where iv/T are the trapezoid-weighted plane reductions. This removes
//      the iv/T workspace round-trip and the second kernel launch entirely.
//   3. Block-reduce 6 scalars (shuffle + LDS), then every thread writes one
//      float4 of each of the two output planes:
//        out[b,o,h,w] = tc[h,w,0]*SX0 + tc[h,w,1]*SX1 + C
__global__ __launch_bounds__(1024) void k_fused(
    const float* __restrict__ v, const float* __restrict__ vc,
    const float* __restrict__ tc, const float* __restrict__ Wx,
    const float* __restrict__ Wy, float* __restrict__ out) {
  const int blk = blockIdx.x;          // 0 .. 255
  const int b   = blk >> 5;            // 32 o-pairs per batch
  const int op  = blk & 31;            // o = 2*op + oo, oo in {0,1}
  const int tid = threadIdx.x;         // 0 .. 1023

  __shared__ float4 wls[2][CI_];       // (wx0, wx1, wy0, wy1) per (oo, i)
  __shared__ float  red[16][8];        // per-wave partials (6 used)
  __shared__ float  bc[2][4];          // final (SX0, SX1, C) per oo

  // ---- coefficient phase: 64 threads, one (oo, i) each ----
  if (tid < 2 * CI_) {
    const int i  = tid & (CI_ - 1);
    const int oo = tid >> 5;
    const int o  = op * 2 + oo;
    float wx0 = 0.f, wx1 = 0.f, wy0 = 0.f, wy1 = 0.f;
#pragma unroll
    for (int f = 0; f < F_; ++f) {
      const int base = ((f * CO_ + o) * CI_ + i) * 2;
      float2 wx = *(const float2*)(Wx + base);
      float2 wy = *(const float2*)(Wy + base);
      wx0 += wx.x; wx1 += wx.y; wy0 += wy.x; wy1 += wy.y;
    }
    wls[oo][i] = make_float4(wx0, wx1, wy0, wy1);
  }

  // ---- per-thread geometry (trapezoid weights + coords) ----
  const int h  = tid >> 4;             // 16 float4 per row
  const int w4 = tid & 15;
#define GW_(w) ((((w) == 0) || ((w) == W_ - 1)) ? 0.5f : 1.0f)
  const int wsc = w4 * 4;
  const float wh = ((h == 0) || (h == H_ - 1)) ? 0.5f : 1.0f;
  const float4 wg = make_float4(wh * GW_(wsc), wh * GW_(wsc + 1),
                                wh * GW_(wsc + 2), wh * GW_(wsc + 3));
  const float cx0 = vc[2 * wsc],       cx1 = vc[2 * (wsc + 1)];
  const float cx2 = vc[2 * (wsc + 2)], cx3 = vc[2 * (wsc + 3)];
  const float cy  = vc[h * (W_ * 2) + 1];

  __syncthreads();

  // ---- main loop over input channels ----
  float a00 = 0.f, a01 = 0.f, aC0 = 0.f;   // oo = 0
  float a10 = 0.f, a11 = 0.f, aC1 = 0.f;   // oo = 1
  const float4* vb = (const float4*)(v + (size_t)b * (CI_ * H_ * W_));
#pragma unroll 8
  for (int i = 0; i < CI_; ++i) {
    float4 a = vb[i * 1024 + tid];
    float t0 = a.x * wg.x, t1 = a.y * wg.y, t2 = a.z * wg.z, t3 = a.w * wg.w;
    float rs0 = (t0 + t1) + (t2 + t3);                       // iv partial
    float rs1 = t0 * cx0 + t1 * cx1 + t2 * cx2 + t3 * cx3;   // T0 partial
    float rs2 = cy * rs0;                                    // T1 partial
    float4 wA = wls[0][i];
    float4 wB = wls[1][i];
    a00 += wA.x * rs0;  a01 += wA.y * rs0;  aC0 += wA.z * rs1 + wA.w * rs2;
    a10 += wB.x * rs0;  a11 += wB.y * rs0;  aC1 += wB.z * rs1 + wB.w * rs2;
  }

  // ---- block reduction: 6 scalars over 1024 threads ----
  for (int off = 32; off > 0; off >>= 1) {
    a00 += __shfl_down(a00, off, 64);
    a01 += __shfl_down(a01, off, 64);
    aC0 += __shfl_down(aC0, off, 64);
    a10 += __shfl_down(a10, off, 64);
    a11 += __shfl_down(a11, off, 64);
    aC1 += __shfl_down(aC1, off, 64);
  }
  const int wave = tid >> 6;
  if ((tid & 63) == 0) {
    red[wave][0] = a00; red[wave][1] = a01; red[wave][2] = aC0;
    red[wave][3] = a10; red[wave][4] = a11; red[wave][5] = aC1;
  }
  __syncthreads();
  if (tid < 16) {                      // all in wave 0
    float r0 = red[tid][0], r1 = red[tid][1], r2 = red[tid][2];
    float r3 = red[tid][3], r4 = red[tid][4], r5 = red[tid][5];
    for (int off = 8; off > 0; off >>= 1) {
      r0 += __shfl_down(r0, off, 64);
      r1 += __shfl_down(r1, off, 64);
      r2 += __shfl_down(r2, off, 64);
      r3 += __shfl_down(r3, off, 64);
      r4 += __shfl_down(r4, off, 64);
      r5 += __shfl_down(r5, off, 64);
    }
    if (tid == 0) {
      const float dx = vc[2] - vc[0];  // uniform grid spacing
      const float sc = dx * dx;
      bc[0][0] = r0 * sc; bc[0][1] = r1 * sc; bc[0][2] = r2 * sc;
      bc[1][0] = r3 * sc; bc[1][1] = r4 * sc; bc[1][2] = r5 * sc;
    }
  }
  __syncthreads();

  // ---- write phase: one float4 per thread per o-plane ----
  const float4* tcp = (const float4*)(tc + (size_t)(h * W_ + wsc) * 2);
  const float4 t0v = tcp[0];           // gx0, gy0, gx1, gy1
  const float4 t1v = tcp[1];           // gx2, gy2, gx3, gy3

  {
    const float SX0 = bc[0][0], SX1 = bc[0][1], C = bc[0][2];
    float4 r;
    r.x = t0v.x * SX0 + t0v.y * SX1 + C;
    r.y = t0v.z * SX0 + t0v.w * SX1 + C;
    r.z = t1v.x * SX0 + t1v.y * SX1 + C;
    r.w = t1v.z * SX0 + t1v.w * SX1 + C;
    ((float4*)out)[(size_t)(b * CO_ + op * 2) * 1024 + tid] = r;
  }
  {
    const float SX0 = bc[1][0], SX1 = bc[1][1], C = bc[1][2];
    float4 r;
    r.x = t0v.x * SX0 + t0v.y * SX1 + C;
    r.y = t0v.z * SX0 + t0v.w * SX1 + C;
    r.z = t1v.x * SX0 + t1v.y * SX1 + C;
    r.w = t1v.z * SX0 + t1v.w * SX1 + C;
    ((float4*)out)[(size_t)(b * CO_ + op * 2 + 1) * 1024 + tid] = r;
  }
}

extern "C" void kernel_launch(void* const* d_in, const int* in_sizes, int n_in,
                              void* d_out, int out_size, void* d_ws, size_t ws_size,
                              hipStream_t stream) {
  const float* v  = (const float*)d_in[0];   // [B,CI,H,W]
  const float* vc = (const float*)d_in[1];   // [H,W,2]
  const float* tc = (const float*)d_in[2];   // [H,W,2]
  const float* Wx = (const float*)d_in[3];   // [F,CO,CI,2]
  const float* Wy = (const float*)d_in[4];   // [F,CO,CI,2]
  float* out = (float*)d_out;                // [B,CO,H,W]

  // Single fused kernel; no workspace, no inter-kernel dependency.
  k_fused<<<B_ * (CO_ / 2), 1024, 0, stream>>>(v, vc, tc, Wx, Wy, out);
}

// Round 2
// 75.882 us; speedup vs baseline: 1.0318x; 1.0318x over previous
//
#include <hip/hip_runtime.h>

#define B_  8
#define CI_ 32
#define CO_ 64
#define F_  4
#define H_  64
#define W_  64

// Fully fused single kernel, XCD-affine mapping. One block per (b, o-pair):
// 256 blocks x 1024 threads (1 block/CU).
//
// KEY CHANGE vs R1: block -> (b, op) mapping is b = blk & 7, op = blk >> 3.
// Consecutive block IDs round-robin across the 8 XCDs (xcd = blk & 7), and
// B == 8, so ALL 32 blocks that stream batch-slice b land on the SAME XCD.
// The 512 KB slice is L2-resident there (4 MiB per-XCD L2), so the 32x
// redundant re-read of v is served at per-XCD L2 bandwidth instead of
// falling through to L3/HBM (which the 256 MiB workspace poison flushes
// every iteration). R1's default mapping spread same-b blocks across all
// 8 XCDs and paid ~27 us of HBM-rate traffic for 134 MB of re-reads.
__global__ __launch_bounds__(1024) void k_fused(
    const float* __restrict__ v, const float* __restrict__ vc,
    const float* __restrict__ tc, const float* __restrict__ Wx,
    const float* __restrict__ Wy, float* __restrict__ out) {
  const int blk = blockIdx.x;          // 0 .. 255
  const int b   = blk & 7;             // XCD-affine: same b -> same XCD
  const int op  = blk >> 3;            // 0 .. 31; o = 2*op + oo, oo in {0,1}
  const int tid = threadIdx.x;         // 0 .. 1023

  __shared__ float4 wls[2][CI_];       // (wx0, wx1, wy0, wy1) per (oo, i)
  __shared__ float  red[16][8];        // per-wave partials (6 used)
  __shared__ float  bc[2][4];          // final (SX0, SX1, C) per oo

  // ---- coefficient phase: 64 threads, one (oo, i) each ----
  if (tid < 2 * CI_) {
    const int i  = tid & (CI_ - 1);
    const int oo = tid >> 5;
    const int o  = op * 2 + oo;
    float wx0 = 0.f, wx1 = 0.f, wy0 = 0.f, wy1 = 0.f;
#pragma unroll
    for (int f = 0; f < F_; ++f) {
      const int base = ((f * CO_ + o) * CI_ + i) * 2;
      float2 wx = *(const float2*)(Wx + base);
      float2 wy = *(const float2*)(Wy + base);
      wx0 += wx.x; wx1 += wx.y; wy0 += wy.x; wy1 += wy.y;
    }
    wls[oo][i] = make_float4(wx0, wx1, wy0, wy1);
  }

  // ---- per-thread geometry (trapezoid weights + coords) ----
  const int h  = tid >> 4;             // 16 float4 per row
  const int w4 = tid & 15;
#define GW_(w) ((((w) == 0) || ((w) == W_ - 1)) ? 0.5f : 1.0f)
  const int wsc = w4 * 4;
  const float wh = ((h == 0) || (h == H_ - 1)) ? 0.5f : 1.0f;
  const float4 wg = make_float4(wh * GW_(wsc), wh * GW_(wsc + 1),
                                wh * GW_(wsc + 2), wh * GW_(wsc + 3));
  const float cx0 = vc[2 * wsc],       cx1 = vc[2 * (wsc + 1)];
  const float cx2 = vc[2 * (wsc + 2)], cx3 = vc[2 * (wsc + 3)];
  const float cy  = vc[h * (W_ * 2) + 1];

  __syncthreads();

  // ---- main loop over input channels (v slice is XCD-local L2-hot) ----
  float a00 = 0.f, a01 = 0.f, aC0 = 0.f;   // oo = 0
  float a10 = 0.f, a11 = 0.f, aC1 = 0.f;   // oo = 1
  const float4* vb = (const float4*)(v + (size_t)b * (CI_ * H_ * W_));
#pragma unroll 8
  for (int i = 0; i < CI_; ++i) {
    float4 a = vb[i * 1024 + tid];
    float t0 = a.x * wg.x, t1 = a.y * wg.y, t2 = a.z * wg.z, t3 = a.w * wg.w;
    float rs0 = (t0 + t1) + (t2 + t3);                       // iv partial
    float rs1 = t0 * cx0 + t1 * cx1 + t2 * cx2 + t3 * cx3;   // T0 partial
    float rs2 = cy * rs0;                                    // T1 partial
    float4 wA = wls[0][i];
    float4 wB = wls[1][i];
    a00 += wA.x * rs0;  a01 += wA.y * rs0;  aC0 += wA.z * rs1 + wA.w * rs2;
    a10 += wB.x * rs0;  a11 += wB.y * rs0;  aC1 += wB.z * rs1 + wB.w * rs2;
  }

  // ---- block reduction: 6 scalars over 1024 threads ----
  for (int off = 32; off > 0; off >>= 1) {
    a00 += __shfl_down(a00, off, 64);
    a01 += __shfl_down(a01, off, 64);
    aC0 += __shfl_down(aC0, off, 64);
    a10 += __shfl_down(a10, off, 64);
    a11 += __shfl_down(a11, off, 64);
    aC1 += __shfl_down(aC1, off, 64);
  }
  const int wave = tid >> 6;
  if ((tid & 63) == 0) {
    red[wave][0] = a00; red[wave][1] = a01; red[wave][2] = aC0;
    red[wave][3] = a10; red[wave][4] = a11; red[wave][5] = aC1;
  }
  __syncthreads();
  if (tid < 16) {                      // all in wave 0
    float r0 = red[tid][0], r1 = red[tid][1], r2 = red[tid][2];
    float r3 = red[tid][3], r4 = red[tid][4], r5 = red[tid][5];
    for (int off = 8; off > 0; off >>= 1) {
      r0 += __shfl_down(r0, off, 64);
      r1 += __shfl_down(r1, off, 64);
      r2 += __shfl_down(r2, off, 64);
      r3 += __shfl_down(r3, off, 64);
      r4 += __shfl_down(r4, off, 64);
      r5 += __shfl_down(r5, off, 64);
    }
    if (tid == 0) {
      const float dx = vc[2] - vc[0];  // uniform grid spacing
      const float sc = dx * dx;
      bc[0][0] = r0 * sc; bc[0][1] = r1 * sc; bc[0][2] = r2 * sc;
      bc[1][0] = r3 * sc; bc[1][1] = r4 * sc; bc[1][2] = r5 * sc;
    }
  }
  __syncthreads();

  // ---- write phase: one float4 per thread per o-plane ----
  const float4* tcp = (const float4*)(tc + (size_t)(h * W_ + wsc) * 2);
  const float4 t0v = tcp[0];           // gx0, gy0, gx1, gy1
  const float4 t1v = tcp[1];           // gx2, gy2, gx3, gy3

  {
    const float SX0 = bc[0][0], SX1 = bc[0][1], C = bc[0][2];
    float4 r;
    r.x = t0v.x * SX0 + t0v.y * SX1 + C;
    r.y = t0v.z * SX0 + t0v.w * SX1 + C;
    r.z = t1v.x * SX0 + t1v.y * SX1 + C;
    r.w = t1v.z * SX0 + t1v.w * SX1 + C;
    ((float4*)out)[(size_t)(b * CO_ + op * 2) * 1024 + tid] = r;
  }
  {
    const float SX0 = bc[1][0], SX1 = bc[1][1], C = bc[1][2];
    float4 r;
    r.x = t0v.x * SX0 + t0v.y * SX1 + C;
    r.y = t0v.z * SX0 + t0v.w * SX1 + C;
    r.z = t1v.x * SX0 + t1v.y * SX1 + C;
    r.w = t1v.z * SX0 + t1v.w * SX1 + C;
    ((float4*)out)[(size_t)(b * CO_ + op * 2 + 1) * 1024 + tid] = r;
  }
}

extern "C" void kernel_launch(void* const* d_in, const int* in_sizes, int n_in,
                              void* d_out, int out_size, void* d_ws, size_t ws_size,
                              hipStream_t stream) {
  const float* v  = (const float*)d_in[0];   // [B,CI,H,W]
  const float* vc = (const float*)d_in[1];   // [H,W,2]
  const float* tc = (const float*)d_in[2];   // [H,W,2]
  const float* Wx = (const float*)d_in[3];   // [F,CO,CI,2]
  const float* Wy = (const float*)d_in[4];   // [F,CO,CI,2]
  float* out = (float*)d_out;                // [B,CO,H,W]

  // Single fused kernel; no workspace, no inter-kernel dependency.
  k_fused<<<B_ * (CO_ / 2), 1024, 0, stream>>>(v, vc, tc, Wx, Wy, out);
}